// Round 4
// baseline (81.926 us; speedup 1.0000x reference)
//
#include <hip/hip_runtime.h>

// K[b,i,j] = exp(-|xi-xj|^2/2), points [4,4096,64] fp32, out [4,4096,4096] fp32.
// Single bf16 MFMA Gram GEMM; norms computed from the SAME bf16 values so
// inner - na - nb == -0.5*|hi(x)-hi(y)|^2 algebraically; diagonal forced to 1.
// MFMA operands SWAPPED (mfma(b,a)) so each thread's 4 acc regs are 4
// consecutive output columns -> float4 nontemporal stores.

#define NPTS 4096
#define DDIM 64
#define BT 128
#define NTB (NPTS / BT)   // 32

typedef __attribute__((ext_vector_type(8))) short bf16x8;
typedef __attribute__((ext_vector_type(4))) float f32x4;

__device__ __forceinline__ ushort bf16_rne(float x) {
    union { float f; unsigned u; } v; v.f = x;
    unsigned r = v.u + 0x7fffu + ((v.u >> 16) & 1u);
    return (ushort)(r >> 16);
}
__device__ __forceinline__ float bf16_f(ushort b) {
    union { float f; unsigned u; } v; v.u = ((unsigned)b) << 16;
    return v.f;
}

// fp32 -> bf16 (RNE), linear [4*4096][64].
__global__ __launch_bounds__(256)
void KernelDistance_pack(const float* __restrict__ pts, ushort* __restrict__ hi) {
    const int gid = blockIdx.x * 256 + threadIdx.x;      // [0, 131072)
    const float4* src = (const float4*)pts + (size_t)gid * 2;
    const float4 v0 = src[0], v1 = src[1];
    const float f[8] = {v0.x, v0.y, v0.z, v0.w, v1.x, v1.y, v1.z, v1.w};
    union { ushort us[8]; bf16x8 v; } H;
#pragma unroll
    for (int j = 0; j < 8; ++j) H.us[j] = bf16_rne(f[j]);
    *(bf16x8*)(hi + (size_t)gid * 8) = H.v;
}

template <bool PACKED>
__global__ __launch_bounds__(256)
void KernelDistance_74972949119307_kernel(const float* __restrict__ pts,
                                          const ushort* __restrict__ hi,
                                          float* __restrict__ out) {
    // 16 KB + 16 KB tiles, chunk-XOR swizzle c' = c ^ (row&7); + 1 KB norms.
    __shared__ ushort Ah[BT * DDIM];
    __shared__ ushort Bh[BT * DDIM];
    __shared__ float na_s[BT];
    __shared__ float nb_s[BT];

    const int bx = blockIdx.x, by = blockIdx.y, bz = blockIdx.z;
    const int tid = threadIdx.x;

    // ---- Stage A/B tiles (bf16) + per-row half-norms from the bf16 values ----
#pragma unroll
    for (int tile = 0; tile < 2; ++tile) {
        const size_t rowbase = ((size_t)bz * NPTS + (size_t)(tile ? bx : by) * BT) * DDIM;
        ushort* L = tile ? Bh : Ah;
        float* ns = tile ? nb_s : na_s;
#pragma unroll
        for (int k = 0; k < 4; ++k) {
            const int f = k * 256 + tid;       // 16B chunk index [0,1024)
            const int row = f >> 3;            // [0,128)
            const int c = f & 7;               // logical chunk in row
            union { ushort us[8]; bf16x8 v; } H;
            if (PACKED) {
                H.v = *(const bf16x8*)(hi + rowbase + (size_t)f * 8);
            } else {
                const float4* g = (const float4*)(pts + rowbase) + (size_t)f * 2;
                const float4 v0 = g[0], v1 = g[1];
                const float fv[8] = {v0.x, v0.y, v0.z, v0.w, v1.x, v1.y, v1.z, v1.w};
#pragma unroll
                for (int j = 0; j < 8; ++j) H.us[j] = bf16_rne(fv[j]);
            }
            float s = 0.f;
#pragma unroll
            for (int j = 0; j < 8; ++j) {
                const float x = bf16_f(H.us[j]);
                s += x * x;
            }
            s += __shfl_xor(s, 1);
            s += __shfl_xor(s, 2);
            s += __shfl_xor(s, 4);
            *(bf16x8*)&L[row * 64 + (c ^ (row & 7)) * 8] = H.v;
            if (c == 0) ns[row] = 0.5f * s;
        }
    }
    __syncthreads();

    // ---- 4 waves 2x2, each 64x64 = 4x4 tiles of 16x16, K=64 in two steps ----
    const int lane = tid & 63;
    const int wid = tid >> 6;
    const int wm = (wid >> 1) * 64;
    const int wn = (wid & 1) * 64;
    const int ml = lane & 15;
    const int g = lane >> 4;

    f32x4 acc[4][4];
#pragma unroll
    for (int mt = 0; mt < 4; ++mt)
#pragma unroll
        for (int nt = 0; nt < 4; ++nt)
            acc[mt][nt] = (f32x4){0.f, 0.f, 0.f, 0.f};

#pragma unroll
    for (int s = 0; s < 2; ++s) {
        bf16x8 a[4], b[4];
#pragma unroll
        for (int mt = 0; mt < 4; ++mt) {
            const int row = wm + mt * 16 + ml;
            const int c = (4 * s + g) ^ (row & 7);
            a[mt] = *(const bf16x8*)&Ah[row * 64 + c * 8];
        }
#pragma unroll
        for (int nt = 0; nt < 4; ++nt) {
            const int row = wn + nt * 16 + ml;
            const int c = (4 * s + g) ^ (row & 7);
            b[nt] = *(const bf16x8*)&Bh[row * 64 + c * 8];
        }
        // Swapped operands: C row <-> b's row (j), C col <-> a's row (i).
#pragma unroll
        for (int mt = 0; mt < 4; ++mt)
#pragma unroll
            for (int nt = 0; nt < 4; ++nt)
                acc[mt][nt] = __builtin_amdgcn_mfma_f32_16x16x32_bf16(b[nt], a[mt], acc[mt][nt], 0, 0, 0);
    }

    // ---- Epilogue: thread owns (i = wm+mt*16+ml, j = wn+nt*16+g*4+reg) ----
    f32x4 nbq[4];
#pragma unroll
    for (int nt = 0; nt < 4; ++nt)
        nbq[nt] = *(const f32x4*)&nb_s[wn + nt * 16 + g * 4];

    float* outB = out + ((size_t)bz * NPTS + (size_t)by * BT) * NPTS + (size_t)bx * BT;
    const bool diagblk = (bx == by);

#pragma unroll
    for (int mt = 0; mt < 4; ++mt) {
        const int i = wm + mt * 16 + ml;
        const float nav = na_s[i];
        float* orow = outB + (size_t)i * NPTS;
#pragma unroll
        for (int nt = 0; nt < 4; ++nt) {
            const int j0 = wn + nt * 16 + g * 4;
            f32x4 o;
#pragma unroll
            for (int r = 0; r < 4; ++r) {
                const float v = acc[mt][nt][r] - (nav + nbq[nt][r]);
                o[r] = __expf(fminf(v, 0.f));
            }
            if (diagblk) {
                const int d = i - j0;
                o[0] = (d == 0) ? 1.0f : o[0];
                o[1] = (d == 1) ? 1.0f : o[1];
                o[2] = (d == 2) ? 1.0f : o[2];
                o[3] = (d == 3) ? 1.0f : o[3];
            }
            __builtin_nontemporal_store(o, (f32x4*)&orow[j0]);
        }
    }
}

extern "C" void kernel_launch(void* const* d_in, const int* in_sizes, int n_in,
                              void* d_out, int out_size, void* d_ws, size_t ws_size,
                              hipStream_t stream) {
    const float* pts = (const float*)d_in[0];
    float* out = (float*)d_out;
    ushort* hi = (ushort*)d_ws;
    const size_t need = (size_t)4 * NPTS * DDIM * sizeof(ushort);   // 2 MB

    dim3 grid(NTB, NTB, 4);
    if (ws_size >= need) {
        KernelDistance_pack<<<512, 256, 0, stream>>>(pts, hi);
        KernelDistance_74972949119307_kernel<true><<<grid, 256, 0, stream>>>(pts, hi, out);
    } else {
        KernelDistance_74972949119307_kernel<false><<<grid, 256, 0, stream>>>(pts, nullptr, out);
    }
}

// Round 5
// 63.289 us; speedup vs baseline: 1.2945x; 1.2945x over previous
//
#include <hip/hip_runtime.h>

// K[b,i,j] = exp(-|xi-xj|^2/2), points [4,4096,64] fp32, out [4,4096,4096] fp32.
// Single bf16 MFMA Gram GEMM; norms computed from the SAME bf16 values so
// inner - na - nb == -0.5*|hi(x)-hi(y)|^2 algebraically; diagonal forced to 1.
// MFMA operands swapped (mfma(b,a)) so each thread's 4 acc regs are 4
// consecutive output columns -> plain (cached) float4 stores.
// NOTE: nontemporal stores REGRESSED (82 vs 60 us) - they defeat L2 write
// aggregation; fill-rate ceiling (7 TB/s) is only reachable with cached stores.

#define NPTS 4096
#define DDIM 64
#define BT 128
#define NTB (NPTS / BT)   // 32

typedef __attribute__((ext_vector_type(8))) short bf16x8;
typedef __attribute__((ext_vector_type(4))) float f32x4;

__device__ __forceinline__ ushort bf16_rne(float x) {
    union { float f; unsigned u; } v; v.f = x;
    unsigned r = v.u + 0x7fffu + ((v.u >> 16) & 1u);
    return (ushort)(r >> 16);
}
__device__ __forceinline__ float bf16_f(ushort b) {
    union { float f; unsigned u; } v; v.u = ((unsigned)b) << 16;
    return v.f;
}

// fp32 -> bf16 (RNE), linear [4*4096][64].
__global__ __launch_bounds__(256)
void KernelDistance_pack(const float* __restrict__ pts, ushort* __restrict__ hi) {
    const int gid = blockIdx.x * 256 + threadIdx.x;      // [0, 131072)
    const float4* src = (const float4*)pts + (size_t)gid * 2;
    const float4 v0 = src[0], v1 = src[1];
    const float f[8] = {v0.x, v0.y, v0.z, v0.w, v1.x, v1.y, v1.z, v1.w};
    union { ushort us[8]; bf16x8 v; } H;
#pragma unroll
    for (int j = 0; j < 8; ++j) H.us[j] = bf16_rne(f[j]);
    *(bf16x8*)(hi + (size_t)gid * 8) = H.v;
}

template <bool PACKED>
__global__ __launch_bounds__(256)
void KernelDistance_74972949119307_kernel(const float* __restrict__ pts,
                                          const ushort* __restrict__ hi,
                                          float* __restrict__ out) {
    // 16 KB + 16 KB tiles, chunk-XOR swizzle c' = c ^ (row&7); + 1 KB norms.
    __shared__ ushort Ah[BT * DDIM];
    __shared__ ushort Bh[BT * DDIM];
    __shared__ float na_s[BT];
    __shared__ float nb_s[BT];

    const int bx = blockIdx.x, by = blockIdx.y, bz = blockIdx.z;
    const int tid = threadIdx.x;

    // ---- Stage A/B tiles (bf16) + per-row half-norms from the bf16 values ----
#pragma unroll
    for (int tile = 0; tile < 2; ++tile) {
        const size_t rowbase = ((size_t)bz * NPTS + (size_t)(tile ? bx : by) * BT) * DDIM;
        ushort* L = tile ? Bh : Ah;
        float* ns = tile ? nb_s : na_s;
#pragma unroll
        for (int k = 0; k < 4; ++k) {
            const int f = k * 256 + tid;       // 16B chunk index [0,1024)
            const int row = f >> 3;            // [0,128)
            const int c = f & 7;               // logical chunk in row
            union { ushort us[8]; bf16x8 v; } H;
            if (PACKED) {
                H.v = *(const bf16x8*)(hi + rowbase + (size_t)f * 8);
            } else {
                const float4* g = (const float4*)(pts + rowbase) + (size_t)f * 2;
                const float4 v0 = g[0], v1 = g[1];
                const float fv[8] = {v0.x, v0.y, v0.z, v0.w, v1.x, v1.y, v1.z, v1.w};
#pragma unroll
                for (int j = 0; j < 8; ++j) H.us[j] = bf16_rne(fv[j]);
            }
            float s = 0.f;
#pragma unroll
            for (int j = 0; j < 8; ++j) {
                const float x = bf16_f(H.us[j]);
                s += x * x;
            }
            s += __shfl_xor(s, 1);
            s += __shfl_xor(s, 2);
            s += __shfl_xor(s, 4);
            *(bf16x8*)&L[row * 64 + (c ^ (row & 7)) * 8] = H.v;
            if (c == 0) ns[row] = 0.5f * s;
        }
    }
    __syncthreads();

    // ---- 4 waves 2x2, each 64x64 = 4x4 tiles of 16x16, K=64 in two steps ----
    const int lane = tid & 63;
    const int wid = tid >> 6;
    const int wm = (wid >> 1) * 64;
    const int wn = (wid & 1) * 64;
    const int ml = lane & 15;
    const int g = lane >> 4;

    f32x4 acc[4][4];
#pragma unroll
    for (int mt = 0; mt < 4; ++mt)
#pragma unroll
        for (int nt = 0; nt < 4; ++nt)
            acc[mt][nt] = (f32x4){0.f, 0.f, 0.f, 0.f};

#pragma unroll
    for (int s = 0; s < 2; ++s) {
        bf16x8 a[4], b[4];
#pragma unroll
        for (int mt = 0; mt < 4; ++mt) {
            const int row = wm + mt * 16 + ml;
            const int c = (4 * s + g) ^ (row & 7);
            a[mt] = *(const bf16x8*)&Ah[row * 64 + c * 8];
        }
#pragma unroll
        for (int nt = 0; nt < 4; ++nt) {
            const int row = wn + nt * 16 + ml;
            const int c = (4 * s + g) ^ (row & 7);
            b[nt] = *(const bf16x8*)&Bh[row * 64 + c * 8];
        }
        // Swapped operands: C row <-> b's row (j), C col <-> a's row (i).
#pragma unroll
        for (int mt = 0; mt < 4; ++mt)
#pragma unroll
            for (int nt = 0; nt < 4; ++nt)
                acc[mt][nt] = __builtin_amdgcn_mfma_f32_16x16x32_bf16(b[nt], a[mt], acc[mt][nt], 0, 0, 0);
    }

    // ---- Epilogue: thread owns (i = wm+mt*16+ml, j = wn+nt*16+g*4+reg) ----
    f32x4 nbq[4];
#pragma unroll
    for (int nt = 0; nt < 4; ++nt)
        nbq[nt] = *(const f32x4*)&nb_s[wn + nt * 16 + g * 4];

    float* outB = out + ((size_t)bz * NPTS + (size_t)by * BT) * NPTS + (size_t)bx * BT;
    const bool diagblk = (bx == by);

#pragma unroll
    for (int mt = 0; mt < 4; ++mt) {
        const int i = wm + mt * 16 + ml;
        const float nav = na_s[i];
        float* orow = outB + (size_t)i * NPTS;
#pragma unroll
        for (int nt = 0; nt < 4; ++nt) {
            const int j0 = wn + nt * 16 + g * 4;
            f32x4 o;
#pragma unroll
            for (int r = 0; r < 4; ++r) {
                const float v = acc[mt][nt][r] - (nav + nbq[nt][r]);
                o[r] = __expf(fminf(v, 0.f));
            }
            if (diagblk) {
                const int d = i - j0;
                o[0] = (d == 0) ? 1.0f : o[0];
                o[1] = (d == 1) ? 1.0f : o[1];
                o[2] = (d == 2) ? 1.0f : o[2];
                o[3] = (d == 3) ? 1.0f : o[3];
            }
            *(f32x4*)&orow[j0] = o;   // plain cached store (nt regressed)
        }
    }
}

extern "C" void kernel_launch(void* const* d_in, const int* in_sizes, int n_in,
                              void* d_out, int out_size, void* d_ws, size_t ws_size,
                              hipStream_t stream) {
    const float* pts = (const float*)d_in[0];
    float* out = (float*)d_out;
    ushort* hi = (ushort*)d_ws;
    const size_t need = (size_t)4 * NPTS * DDIM * sizeof(ushort);   // 2 MB

    dim3 grid(NTB, NTB, 4);
    if (ws_size >= need) {
        KernelDistance_pack<<<512, 256, 0, stream>>>(pts, hi);
        KernelDistance_74972949119307_kernel<true><<<grid, 256, 0, stream>>>(pts, hi, out);
    } else {
        KernelDistance_74972949119307_kernel<false><<<grid, 256, 0, stream>>>(pts, nullptr, out);
    }
}